// Round 12
// baseline (453.271 us; speedup 1.0000x reference)
//
#include <hip/hip_runtime.h>
#include <hip/hip_fp8.h>

#define N_ROWS 4096
#define H_DIM  1024
#define V_SIZE 32000

typedef int   i32x4 __attribute__((ext_vector_type(4)));
typedef int   i32x8 __attribute__((ext_vector_type(8)));
typedef float f32x4 __attribute__((ext_vector_type(4)));

typedef __attribute__((address_space(1))) void* gas_ptr;
typedef __attribute__((address_space(3))) void* las_ptr;

__global__ void zero_f32(float* __restrict__ p, int n) {
  int i = blockIdx.x * blockDim.x + threadIdx.x;
  if (i < n) p[i] = 0.0f;
}

__device__ __forceinline__ unsigned pk4_fp8(float a, float b, float c, float d) {
#if __has_builtin(__builtin_amdgcn_cvt_pk_fp8_f32)
  int v = __builtin_amdgcn_cvt_pk_fp8_f32(a, b, 0, false);
  v = __builtin_amdgcn_cvt_pk_fp8_f32(c, d, v, true);
  return (unsigned)v;
#else
  __hip_fp8_e4m3 qa(a), qb(b), qc(c), qd(d);
  return (unsigned)qa.__x | ((unsigned)qb.__x << 8) | ((unsigned)qc.__x << 16) |
         ((unsigned)qd.__x << 24);
#endif
}

// W path (Ws/Wt): fp32 -> fp8 e4m3 with the LDS swizzle PRE-BAKED:
// out[row*1024 + (k ^ ((row&7)<<4))] = fp8(in[row*1024 + k]).  (r9-verified)
__global__ void cvt_fp8(const float* __restrict__ in, unsigned char* __restrict__ out, int total16) {
  int idx = blockIdx.x * blockDim.x + threadIdx.x;
  int stride = gridDim.x * blockDim.x;
  for (; idx < total16; idx += stride) {
    unsigned row = (unsigned)idx >> 6;
    unsigned k0 = ((unsigned)idx & 63u) << 4;
    const float4* p = (const float4*)(in + (size_t)row * H_DIM + k0);
    float4 f0 = p[0], f1 = p[1], f2 = p[2], f3 = p[3];
    unsigned long long u0 = (unsigned long long)pk4_fp8(f0.x, f0.y, f0.z, f0.w) |
                            ((unsigned long long)pk4_fp8(f1.x, f1.y, f1.z, f1.w) << 32);
    unsigned long long u1 = (unsigned long long)pk4_fp8(f2.x, f2.y, f2.z, f2.w) |
                            ((unsigned long long)pk4_fp8(f3.x, f3.y, f3.z, f3.w) << 32);
    unsigned key = (row & 7u) << 4;
    unsigned char* ob = out + (size_t)row * H_DIM;
    *(unsigned long long*)(ob + (k0 ^ key)) = u0;
    *(unsigned long long*)(ob + ((k0 ^ key) + 8u)) = u1;
  }
}

// A path (x/tx): fp32 -> fp8 in FRAGMENT-LINEAR layout so each MFMA A-fragment
// is ONE perfectly coalesced global_load_dwordx4 (no LDS round-trip):
// out[(row>>4)*16384 + kt*2048 + u*256 + (row&15)*16 + b] = fp8(in[row][kt*128+u*16+b])
// Wave read at voffset = base + lane*16 (+1024 for kk2=1) gives lane (c,g)
// logical K-units {g, g+4} of row c -- identical mapping to the B-side LDS
// stream (r9-verified), so the K=128 contraction is exact.
__global__ void cvt_fragA(const float* __restrict__ in, unsigned char* __restrict__ out, int total16) {
  int idx = blockIdx.x * blockDim.x + threadIdx.x;
  int stride = gridDim.x * blockDim.x;
  for (; idx < total16; idx += stride) {
    unsigned row = (unsigned)idx >> 6;
    unsigned u16 = (unsigned)idx & 63u;
    const float4* p = (const float4*)(in + (size_t)row * H_DIM + u16 * 16u);
    float4 f0 = p[0], f1 = p[1], f2 = p[2], f3 = p[3];
    uint4 o;
    o.x = pk4_fp8(f0.x, f0.y, f0.z, f0.w);
    o.y = pk4_fp8(f1.x, f1.y, f1.z, f1.w);
    o.z = pk4_fp8(f2.x, f2.y, f2.z, f2.w);
    o.w = pk4_fp8(f3.x, f3.y, f3.z, f3.w);
    unsigned rg = row >> 4, c = row & 15u, kt = u16 >> 3, u = u16 & 7u;
    *(uint4*)(out + rg * 16384u + kt * 2048u + u * 256u + c * 16u) = o;
  }
}

__device__ __forceinline__ i32x8 cat8(i32x4 a, i32x4 b) {
  return __builtin_shufflevector(a, b, 0, 1, 2, 3, 4, 5, 6, 7);
}

// MX-scaled fp8 MFMA, unit scales (E8M0 127 = x1.0). Validated r8/r9.
__device__ __forceinline__ f32x4 mx_mfma(i32x8 a, i32x8 b, f32x4 c) {
  return __builtin_amdgcn_mfma_scale_f32_16x16x128_f8f6f4(
      a, b, c, 0 /*A=fp8*/, 0 /*B=fp8*/, 0, 0x7f7f7f7f, 0, 0x7f7f7f7f);
}

// Fused dual-GEMM (MX-fp8 16x16x128) + KL partial sums.
// BM=128 x BN=128, 4 waves (2x2 of 64x64), 2 blocks/CU.
// A-operands (x,tx) load STRAIGHT from L2 (fragment-linear layout, coalesced);
// only W tiles go through LDS: double-buffered 2 x (Ws 16KB + Wt 16KB) = 64KB.
// Single barrier per k-step: issue A-loads(t) + W-stage(t+1 -> buf^1), then
// ds_read B(t, buf) interleaved with MFMAs (compiler-counted waits), then
// __syncthreads (drains the stage issued a full step earlier ~ free).
// B ds_read stream = r9's (HW-verified 0 bank conflicts).
__global__ __launch_bounds__(256, 2) void fused_kl(
    const unsigned char* __restrict__ xF, const unsigned char* __restrict__ txF,
    const unsigned char* __restrict__ ws8, const unsigned char* __restrict__ wt8,
    float* __restrict__ Zt, float* __restrict__ Uu, float* __restrict__ Zs) {
  __shared__ __align__(16) char smem[65536];  // buf0: Ws@0,Wt@16K | buf1: Ws@32K,Wt@48K

  const unsigned tid = threadIdx.x;
  const unsigned lane = tid & 63u;
  const unsigned w = tid >> 6;
  const unsigned wr = w >> 1, wc = w & 1u;

  const unsigned b = blockIdx.x;
  const unsigned rb = (b & 7u) * 4u + ((b >> 3) & 3u);  // row-block 0..31
  const unsigned chunk = b >> 5;                        // vocab chunk 0..15
  const unsigned row0 = rb * 128u;
  const unsigned t_begin = chunk * 15u + (chunk < 10u ? chunk : 10u);
  const unsigned t_count = (chunk < 10u) ? 16u : 15u;
  const unsigned NK = t_count * 8u;

  const unsigned c = lane & 15u;
  const unsigned g = (lane >> 4) & 3u;
  const unsigned key = (c & 7u) << 4;

  // B ds_read base pointers per buffer per kk2 (r9-identical relative stream).
  const char* pB[2][2];
#pragma unroll
  for (int bf = 0; bf < 2; ++bf)
#pragma unroll
    for (int kk2 = 0; kk2 < 2; ++kk2) {
      unsigned f = (((unsigned)kk2 << 6) | (g << 4)) ^ key;
      pB[bf][kk2] = smem + (unsigned)bf * 32768u + (wc * 64u + c) * 128u + f;
    }

  // A fragment-linear bases: row-group rg0 = rb*8 + wr*4; fragment (mi,kk2)
  // at (rg0+mi)*16384 + kt*2048 + kk2*1024 + lane*16.
  const unsigned aoff0 = (rb * 8u + wr * 4u) * 16384u + lane * 16u;

  // W staging: wave w stages 8KB of next step's W tiles (linear LDS dest,
  // pre-swizzled source): w0/w1 -> Ws rows 0-63/64-127; w2/w3 -> Wt.
  const unsigned char* gW = (w < 2u) ? ws8 : wt8;
  const unsigned wrow0 = (w & 1u) * 64u;
  const unsigned srow = lane >> 3;
  const unsigned sb = (lane & 7u) * 16u;
  char* sdst0 = smem + ((w >= 2u) ? 16384u : 0u) + (w & 1u) * 8192u + lane * 16u;

  auto issue_stage = [&](unsigned step) {
    unsigned vtp = step >> 3, ktp = step & 7u;
    char* dst = sdst0 + ((step & 1u) ? 32768u : 0u);
    const unsigned char* s0 =
        gW + (size_t)((t_begin + vtp) * 128u + wrow0 + srow) * H_DIM + ktp * 128u + sb;
#pragma unroll
    for (unsigned i = 0; i < 8; ++i)
      __builtin_amdgcn_global_load_lds((gas_ptr)(s0 + (size_t)i * (8u * H_DIM)),
                                       (las_ptr)(dst + i * 1024u), 16, 0, 0);
  };

  float zt1 = 0.f, uu1 = 0.f, zs1 = 0.f;
  const f32x4 fzero = {0.f, 0.f, 0.f, 0.f};
  f32x4 acc_s[4][4], acc_t[4][4];

  // Prologue: stage step-0 W tiles into buf0.
  issue_stage(0);
  __syncthreads();

  for (unsigned t = 0; t < NK; ++t) {
    const unsigned bf = t & 1u;
    const unsigned kt = t & 7u;
    if (kt == 0u) {
#pragma unroll
      for (int mi = 0; mi < 4; ++mi)
#pragma unroll
        for (int ni = 0; ni < 4; ++ni) { acc_s[mi][ni] = fzero; acc_t[mi][ni] = fzero; }
    }

    // Issue student A-loads (coalesced, straight from L2).
    i32x4 ax0[4], ax1[4];
#pragma unroll
    for (int mi = 0; mi < 4; ++mi) {
      const unsigned char* pa = xF + aoff0 + (unsigned)mi * 16384u + kt * 2048u;
      ax0[mi] = *(const i32x4*)pa;
      ax1[mi] = *(const i32x4*)(pa + 1024);
    }
    // Issue next step's W staging into the other buffer (in flight across
    // this whole step; drained by the end-of-step __syncthreads).
    if (t + 1u < NK) issue_stage(t + 1u);

    // ---- student: ds_read B + MFMA (compiler interleaves, counted waits) ----
    {
      const char* q0 = pB[bf][0];
      const char* q1 = pB[bf][1];
      __builtin_amdgcn_s_setprio(1);
#pragma unroll
      for (int ni = 0; ni < 4; ++ni) {
        i32x8 bs = cat8(*(const i32x4*)(q0 + ni * 2048),
                        *(const i32x4*)(q1 + ni * 2048));
#pragma unroll
        for (int mi = 0; mi < 4; ++mi)
          acc_s[mi][ni] = mx_mfma(cat8(ax0[mi], ax1[mi]), bs, acc_s[mi][ni]);
      }
      __builtin_amdgcn_s_setprio(0);
    }

    // Issue teacher A-loads (latency hidden under student MFMAs/reads).
    i32x4 at0[4], at1[4];
#pragma unroll
    for (int mi = 0; mi < 4; ++mi) {
      const unsigned char* pa = txF + aoff0 + (unsigned)mi * 16384u + kt * 2048u;
      at0[mi] = *(const i32x4*)pa;
      at1[mi] = *(const i32x4*)(pa + 1024);
    }
    // ---- teacher: ds_read B (+16384 imm) + MFMA ----
    {
      const char* q0 = pB[bf][0];
      const char* q1 = pB[bf][1];
      __builtin_amdgcn_s_setprio(1);
#pragma unroll
      for (int ni = 0; ni < 4; ++ni) {
        i32x8 bt = cat8(*(const i32x4*)(q0 + ni * 2048 + 16384),
                        *(const i32x4*)(q1 + ni * 2048 + 16384));
#pragma unroll
        for (int mi = 0; mi < 4; ++mi)
          acc_t[mi][ni] = mx_mfma(cat8(at0[mi], at1[mi]), bt, acc_t[mi][ni]);
      }
      __builtin_amdgcn_s_setprio(0);
    }

    // ---- per-vocab-tile epilogue (registers only) ----
    if (kt == 7u) {
      // C/D layout: col = lane&15, row = (lane>>4)*4 + j (m89-verified)
#pragma unroll
      for (int mi = 0; mi < 4; ++mi)
#pragma unroll
        for (int j = 0; j < 4; ++j) {
          float ztl = 0.f, uul = 0.f, zsl = 0.f;
#pragma unroll
          for (int ni = 0; ni < 4; ++ni) {
            float s = acc_s[mi][ni][j];
            float tt = acc_t[mi][ni][j];
            float et = __expf(tt);
            ztl += et;
            uul += et * (tt - s);
            zsl += __expf(s);
          }
          ztl += __shfl_xor(ztl, 1); ztl += __shfl_xor(ztl, 2);
          ztl += __shfl_xor(ztl, 4); ztl += __shfl_xor(ztl, 8);
          uul += __shfl_xor(uul, 1); uul += __shfl_xor(uul, 2);
          uul += __shfl_xor(uul, 4); uul += __shfl_xor(uul, 8);
          zsl += __shfl_xor(zsl, 1); zsl += __shfl_xor(zsl, 2);
          zsl += __shfl_xor(zsl, 4); zsl += __shfl_xor(zsl, 8);
          if (c == (unsigned)(mi * 4 + j)) { zt1 += ztl; uu1 += uul; zs1 += zsl; }
        }
    }

    __syncthreads();  // reads of buf done; stage(t+1) drained (issued ~full step ago)
  }

  // Lane (g,c) owns row: wr*64 + (c>>2)*16 + g*4 + (c&3)  (bijective over 64 rows)
  {
    unsigned n = row0 + wr * 64u + (c >> 2) * 16u + g * 4u + (c & 3u);
    atomicAdd(&Zt[n], zt1);
    atomicAdd(&Uu[n], uu1);
    atomicAdd(&Zs[n], zs1);
  }
}

// KL_n = U/Zt - log Zt + log Zs ; out = mean over N, float32.
__global__ void finalize_kl(const float* __restrict__ Zt, const float* __restrict__ Uu,
                            const float* __restrict__ Zs, float* __restrict__ out) {
  __shared__ float red[4];
  float s = 0.f;
  for (int r = threadIdx.x; r < N_ROWS; r += 256) {
    s += Uu[r] / Zt[r] - __logf(Zt[r]) + __logf(Zs[r]);
  }
  s += __shfl_xor(s, 1); s += __shfl_xor(s, 2); s += __shfl_xor(s, 4);
  s += __shfl_xor(s, 8); s += __shfl_xor(s, 16); s += __shfl_xor(s, 32);
  if ((threadIdx.x & 63) == 0) red[threadIdx.x >> 6] = s;
  __syncthreads();
  if (threadIdx.x == 0) {
    float tot = red[0] + red[1] + red[2] + red[3];
    out[0] = tot / (float)N_ROWS;
  }
}

extern "C" void kernel_launch(void* const* d_in, const int* in_sizes, int n_in,
                              void* d_out, int out_size, void* d_ws, size_t ws_size,
                              hipStream_t stream) {
  const float* x  = (const float*)d_in[0];
  const float* tx = (const float*)d_in[1];
  const float* Ws = (const float*)d_in[2];
  const float* Wt = (const float*)d_in[3];

  char* ws = (char*)d_ws;
  float* Zt = (float*)ws;
  float* Uu = Zt + N_ROWS;
  float* Zs = Uu + N_ROWS;
  unsigned char* xF  = (unsigned char*)(ws + 65536);
  unsigned char* txF = xF  + (size_t)N_ROWS * H_DIM;
  unsigned char* ws8 = txF + (size_t)N_ROWS * H_DIM;
  unsigned char* wt8 = ws8 + (size_t)V_SIZE * H_DIM;

  zero_f32<<<(3 * N_ROWS) / 256, 256, 0, stream>>>(Zt, 3 * N_ROWS);
  cvt_fragA<<<1024, 256, 0, stream>>>(x,  xF,  N_ROWS * (H_DIM / 16));
  cvt_fragA<<<1024, 256, 0, stream>>>(tx, txF, N_ROWS * (H_DIM / 16));
  cvt_fp8<<<2048, 256, 0, stream>>>(Ws, ws8, V_SIZE * (H_DIM / 16));
  cvt_fp8<<<2048, 256, 0, stream>>>(Wt, wt8, V_SIZE * (H_DIM / 16));
  fused_kl<<<512, 256, 0, stream>>>(xF, txF, ws8, wt8, Zt, Uu, Zs);
  finalize_kl<<<1, 256, 0, stream>>>(Zt, Uu, Zs, (float*)d_out);
}

// Round 13
// 429.285 us; speedup vs baseline: 1.0559x; 1.0559x over previous
//
#include <hip/hip_runtime.h>
#include <hip/hip_fp8.h>

#define N_ROWS 4096
#define H_DIM  1024
#define V_SIZE 32000

typedef int   i32x4 __attribute__((ext_vector_type(4)));
typedef int   i32x8 __attribute__((ext_vector_type(8)));
typedef float f32x4 __attribute__((ext_vector_type(4)));

typedef __attribute__((address_space(1))) void* gas_ptr;
typedef __attribute__((address_space(3))) void* las_ptr;

__global__ void zero_f32(float* __restrict__ p, int n) {
  int i = blockIdx.x * blockDim.x + threadIdx.x;
  if (i < n) p[i] = 0.0f;
}

__device__ __forceinline__ unsigned pk4_fp8(float a, float b, float c, float d) {
#if __has_builtin(__builtin_amdgcn_cvt_pk_fp8_f32)
  int v = __builtin_amdgcn_cvt_pk_fp8_f32(a, b, 0, false);
  v = __builtin_amdgcn_cvt_pk_fp8_f32(c, d, v, true);
  return (unsigned)v;
#else
  __hip_fp8_e4m3 qa(a), qb(b), qc(c), qd(d);
  return (unsigned)qa.__x | ((unsigned)qb.__x << 8) | ((unsigned)qc.__x << 16) |
         ((unsigned)qd.__x << 24);
#endif
}

// W path (Ws/Wt): fp32 -> fp8 e4m3 with the LDS swizzle PRE-BAKED (r9-verified):
// out[row*1024 + (k ^ ((row&7)<<4))] = fp8(in[row*1024 + k]).
__global__ void cvt_fp8(const float* __restrict__ in, unsigned char* __restrict__ out, int total16) {
  int idx = blockIdx.x * blockDim.x + threadIdx.x;
  int stride = gridDim.x * blockDim.x;
  for (; idx < total16; idx += stride) {
    unsigned row = (unsigned)idx >> 6;
    unsigned k0 = ((unsigned)idx & 63u) << 4;
    const float4* p = (const float4*)(in + (size_t)row * H_DIM + k0);
    float4 f0 = p[0], f1 = p[1], f2 = p[2], f3 = p[3];
    unsigned long long u0 = (unsigned long long)pk4_fp8(f0.x, f0.y, f0.z, f0.w) |
                            ((unsigned long long)pk4_fp8(f1.x, f1.y, f1.z, f1.w) << 32);
    unsigned long long u1 = (unsigned long long)pk4_fp8(f2.x, f2.y, f2.z, f2.w) |
                            ((unsigned long long)pk4_fp8(f3.x, f3.y, f3.z, f3.w) << 32);
    unsigned key = (row & 7u) << 4;
    unsigned char* ob = out + (size_t)row * H_DIM;
    *(unsigned long long*)(ob + (k0 ^ key)) = u0;
    *(unsigned long long*)(ob + ((k0 ^ key) + 8u)) = u1;
  }
}

// A path (x/tx): fp32 -> fp8 in FRAGMENT-LINEAR layout (r12-verified): each
// MFMA A-fragment is one coalesced global_load_dwordx4 at base + lane*16.
__global__ void cvt_fragA(const float* __restrict__ in, unsigned char* __restrict__ out, int total16) {
  int idx = blockIdx.x * blockDim.x + threadIdx.x;
  int stride = gridDim.x * blockDim.x;
  for (; idx < total16; idx += stride) {
    unsigned row = (unsigned)idx >> 6;
    unsigned u16 = (unsigned)idx & 63u;
    const float4* p = (const float4*)(in + (size_t)row * H_DIM + u16 * 16u);
    float4 f0 = p[0], f1 = p[1], f2 = p[2], f3 = p[3];
    uint4 o;
    o.x = pk4_fp8(f0.x, f0.y, f0.z, f0.w);
    o.y = pk4_fp8(f1.x, f1.y, f1.z, f1.w);
    o.z = pk4_fp8(f2.x, f2.y, f2.z, f2.w);
    o.w = pk4_fp8(f3.x, f3.y, f3.z, f3.w);
    unsigned rg = row >> 4, c = row & 15u, kt = u16 >> 3, u = u16 & 7u;
    *(uint4*)(out + rg * 16384u + kt * 2048u + u * 256u + c * 16u) = o;
  }
}

__device__ __forceinline__ i32x8 cat8(i32x4 a, i32x4 b) {
  return __builtin_shufflevector(a, b, 0, 1, 2, 3, 4, 5, 6, 7);
}

// MX-scaled fp8 MFMA, unit scales (E8M0 127 = x1.0). Validated r8/r9.
__device__ __forceinline__ f32x4 mx_mfma(i32x8 a, i32x8 b, f32x4 c) {
  return __builtin_amdgcn_mfma_scale_f32_16x16x128_f8f6f4(
      a, b, c, 0 /*A=fp8*/, 0 /*B=fp8*/, 0, 0x7f7f7f7f, 0, 0x7f7f7f7f);
}

// Fused dual-GEMM (MX-fp8 16x16x128) + KL partial sums.
// BM=256 x BN=128, 8 waves (4x2 of 64x64), 1 block/CU, grid=256.
// A from L2 (fragment-linear). W double-buffered in LDS (2 x 32KB).
// TRUE counted-wait pipeline (T3/T4, m218): per k-step ONE raw barrier whose
// vmcnt(0) drains only the stage issued a FULL STEP earlier (retired -> free);
// stage(t+1) is issued right after the barrier and flies across the whole
// compute phase. Issue order As(t), At(t), stage(t+1): compiler's automatic
// counted waits give As at vmcnt(12) (~200cy exposed), At at vmcnt(4) (hidden
// under student cluster), stage never waited hot.
__global__ __launch_bounds__(512, 2) void fused_kl(
    const unsigned char* __restrict__ xF, const unsigned char* __restrict__ txF,
    const unsigned char* __restrict__ ws8, const unsigned char* __restrict__ wt8,
    float* __restrict__ Zt, float* __restrict__ Uu, float* __restrict__ Zs) {
  __shared__ __align__(16) char smem[65536];  // buf0: Ws@0,Wt@16K | buf1: @32K,@48K

  const unsigned tid = threadIdx.x;
  const unsigned lane = tid & 63u;
  const unsigned w = tid >> 6;           // wave 0..7
  const unsigned wr = w >> 1, wc = w & 1u;

  const unsigned b = blockIdx.x;
  const unsigned rb = (b & 7u) * 2u + ((b >> 3) & 1u);  // row-block 0..15 (256 rows)
  const unsigned chunk = b >> 4;                        // vocab chunk 0..15
  const unsigned row0 = rb * 256u;
  const unsigned t_begin = chunk * 15u + (chunk < 10u ? chunk : 10u);
  const unsigned t_count = (chunk < 10u) ? 16u : 15u;
  const unsigned NK = t_count * 8u;

  const unsigned c = lane & 15u;
  const unsigned g = (lane >> 4) & 3u;
  const unsigned key = (c & 7u) << 4;

  // B ds_read bases (r9-verified 0-conflict stream); buffer via +(t&1)<<15,
  // Wt via +16384 immediate.
  const char* pB0;
  const char* pB1;
  {
    unsigned f0 = ((0u << 6) | (g << 4)) ^ key;
    unsigned f1 = ((1u << 6) | (g << 4)) ^ key;
    pB0 = smem + (wc * 64u + c) * 128u + f0;
    pB1 = smem + (wc * 64u + c) * 128u + f1;
  }

  // A fragment-linear bases: row-group rg0 = rb*16 + wr*4.
  const unsigned aoff0 = (rb * 16u + wr * 4u) * 16384u + lane * 16u;

  // W staging: waves 0-3 stage Ws rows w*32..+32, waves 4-7 Wt rows (w-4)*32..
  // 4 x global_load_lds(16B) per lane. Linear LDS dest; source pre-swizzled.
  const unsigned char* gW = (w < 4u) ? ws8 : wt8;
  const unsigned wrow0 = (w & 3u) * 32u;
  const unsigned srow = lane >> 3;
  const unsigned sb = (lane & 7u) * 16u;
  char* sdst0 = smem + ((w >= 4u) ? 16384u : 0u) + (w & 3u) * 4096u + lane * 16u;

  auto issue_stage = [&](unsigned step) {
    unsigned vtp = step >> 3, ktp = step & 7u;
    char* dst = sdst0 + ((step & 1u) ? 32768u : 0u);
    const unsigned char* s0 =
        gW + (size_t)((t_begin + vtp) * 128u + wrow0 + srow) * H_DIM + ktp * 128u + sb;
#pragma unroll
    for (unsigned i = 0; i < 4; ++i)
      __builtin_amdgcn_global_load_lds((gas_ptr)(s0 + (size_t)i * (8u * H_DIM)),
                                       (las_ptr)(dst + i * 1024u), 16, 0, 0);
  };

  float zt1 = 0.f, uu1 = 0.f, zs1 = 0.f;
  const f32x4 fzero = {0.f, 0.f, 0.f, 0.f};
  f32x4 acc_s[4][4], acc_t[4][4];

  // Prologue: stage step-0 W into buf0 (the only hot drain, once).
  issue_stage(0);

  for (unsigned t = 0; t < NK; ++t) {
    const unsigned kt = t & 7u;
    const unsigned bfoff = (t & 1u) ? 32768u : 0u;

    // Barrier gate: drains stage(t) (issued a full step ago -> retired, free;
    // at t=0 it's the prologue stage, one real wait). Raw s_barrier needs the
    // explicit vmcnt (compiler only auto-drains for __syncthreads).
    asm volatile("s_waitcnt vmcnt(0)" ::: "memory");
    __builtin_amdgcn_sched_barrier(0);
    __builtin_amdgcn_s_barrier();
    __builtin_amdgcn_sched_barrier(0);

    if (kt == 0u) {
#pragma unroll
      for (int mi = 0; mi < 4; ++mi)
#pragma unroll
        for (int ni = 0; ni < 4; ++ni) { acc_s[mi][ni] = fzero; acc_t[mi][ni] = fzero; }
    }

    // Issue order (FIFO vmcnt): As(t) 8, At(t) 8, stage(t+1) 4.
    i32x4 ax0[4], ax1[4];
#pragma unroll
    for (int mi = 0; mi < 4; ++mi) {
      const unsigned char* pa = xF + aoff0 + (unsigned)mi * 16384u + kt * 2048u;
      ax0[mi] = *(const i32x4*)pa;
      ax1[mi] = *(const i32x4*)(pa + 1024);
    }
    i32x4 at0[4], at1[4];
#pragma unroll
    for (int mi = 0; mi < 4; ++mi) {
      const unsigned char* pa = txF + aoff0 + (unsigned)mi * 16384u + kt * 2048u;
      at0[mi] = *(const i32x4*)pa;
      at1[mi] = *(const i32x4*)(pa + 1024);
    }
    if (t + 1u < NK) issue_stage(t + 1u);

    // ---- student cluster (compiler waits ~vmcnt(12): stage+At stay hot) ----
    {
      const char* q0 = pB0 + bfoff;
      const char* q1 = pB1 + bfoff;
      __builtin_amdgcn_s_setprio(1);
#pragma unroll
      for (int ni = 0; ni < 4; ++ni) {
        i32x8 bs = cat8(*(const i32x4*)(q0 + ni * 2048),
                        *(const i32x4*)(q1 + ni * 2048));
#pragma unroll
        for (int mi = 0; mi < 4; ++mi)
          acc_s[mi][ni] = mx_mfma(cat8(ax0[mi], ax1[mi]), bs, acc_s[mi][ni]);
      }
      __builtin_amdgcn_s_setprio(0);
    }
    // ---- teacher cluster (At hidden under student; Wt via +16384) ----
    {
      const char* q0 = pB0 + bfoff;
      const char* q1 = pB1 + bfoff;
      __builtin_amdgcn_s_setprio(1);
#pragma unroll
      for (int ni = 0; ni < 4; ++ni) {
        i32x8 bt = cat8(*(const i32x4*)(q0 + ni * 2048 + 16384),
                        *(const i32x4*)(q1 + ni * 2048 + 16384));
#pragma unroll
        for (int mi = 0; mi < 4; ++mi)
          acc_t[mi][ni] = mx_mfma(cat8(at0[mi], at1[mi]), bt, acc_t[mi][ni]);
      }
      __builtin_amdgcn_s_setprio(0);
    }

    // ---- per-vocab-tile epilogue (registers only) ----
    if (kt == 7u) {
      // C/D layout: col = lane&15, row = (lane>>4)*4 + j (m89-verified)
#pragma unroll
      for (int mi = 0; mi < 4; ++mi)
#pragma unroll
        for (int j = 0; j < 4; ++j) {
          float ztl = 0.f, uul = 0.f, zsl = 0.f;
#pragma unroll
          for (int ni = 0; ni < 4; ++ni) {
            float s = acc_s[mi][ni][j];
            float tt = acc_t[mi][ni][j];
            float et = __expf(tt);
            ztl += et;
            uul += et * (tt - s);
            zsl += __expf(s);
          }
          ztl += __shfl_xor(ztl, 1); ztl += __shfl_xor(ztl, 2);
          ztl += __shfl_xor(ztl, 4); ztl += __shfl_xor(ztl, 8);
          uul += __shfl_xor(uul, 1); uul += __shfl_xor(uul, 2);
          uul += __shfl_xor(uul, 4); uul += __shfl_xor(uul, 8);
          zsl += __shfl_xor(zsl, 1); zsl += __shfl_xor(zsl, 2);
          zsl += __shfl_xor(zsl, 4); zsl += __shfl_xor(zsl, 8);
          if (c == (unsigned)(mi * 4 + j)) { zt1 += ztl; uu1 += uul; zs1 += zsl; }
        }
    }
  }

  // Lane (g,c) owns row: wr*64 + (c>>2)*16 + g*4 + (c&3)  (bijective over 64 rows)
  {
    unsigned n = row0 + wr * 64u + (c >> 2) * 16u + g * 4u + (c & 3u);
    atomicAdd(&Zt[n], zt1);
    atomicAdd(&Uu[n], uu1);
    atomicAdd(&Zs[n], zs1);
  }
}

// KL_n = U/Zt - log Zt + log Zs ; out = mean over N, float32.
__global__ void finalize_kl(const float* __restrict__ Zt, const float* __restrict__ Uu,
                            const float* __restrict__ Zs, float* __restrict__ out) {
  __shared__ float red[4];
  float s = 0.f;
  for (int r = threadIdx.x; r < N_ROWS; r += 256) {
    s += Uu[r] / Zt[r] - __logf(Zt[r]) + __logf(Zs[r]);
  }
  s += __shfl_xor(s, 1); s += __shfl_xor(s, 2); s += __shfl_xor(s, 4);
  s += __shfl_xor(s, 8); s += __shfl_xor(s, 16); s += __shfl_xor(s, 32);
  if ((threadIdx.x & 63) == 0) red[threadIdx.x >> 6] = s;
  __syncthreads();
  if (threadIdx.x == 0) {
    float tot = red[0] + red[1] + red[2] + red[3];
    out[0] = tot / (float)N_ROWS;
  }
}

extern "C" void kernel_launch(void* const* d_in, const int* in_sizes, int n_in,
                              void* d_out, int out_size, void* d_ws, size_t ws_size,
                              hipStream_t stream) {
  const float* x  = (const float*)d_in[0];
  const float* tx = (const float*)d_in[1];
  const float* Ws = (const float*)d_in[2];
  const float* Wt = (const float*)d_in[3];

  char* ws = (char*)d_ws;
  float* Zt = (float*)ws;
  float* Uu = Zt + N_ROWS;
  float* Zs = Uu + N_ROWS;
  unsigned char* xF  = (unsigned char*)(ws + 65536);
  unsigned char* txF = xF  + (size_t)N_ROWS * H_DIM;
  unsigned char* ws8 = txF + (size_t)N_ROWS * H_DIM;
  unsigned char* wt8 = ws8 + (size_t)V_SIZE * H_DIM;

  zero_f32<<<(3 * N_ROWS) / 256, 256, 0, stream>>>(Zt, 3 * N_ROWS);
  cvt_fragA<<<1024, 256, 0, stream>>>(x,  xF,  N_ROWS * (H_DIM / 16));
  cvt_fragA<<<1024, 256, 0, stream>>>(tx, txF, N_ROWS * (H_DIM / 16));
  cvt_fp8<<<2048, 256, 0, stream>>>(Ws, ws8, V_SIZE * (H_DIM / 16));
  cvt_fp8<<<2048, 256, 0, stream>>>(Wt, wt8, V_SIZE * (H_DIM / 16));
  fused_kl<<<256, 512, 0, stream>>>(xF, txF, ws8, wt8, Zt, Uu, Zs);
  finalize_kl<<<1, 256, 0, stream>>>(Zt, Uu, Zs, (float*)d_out);
}